// Round 13
// baseline (242.130 us; speedup 1.0000x reference)
//
#include <hip/hip_runtime.h>
#include <stdint.h>

typedef __attribute__((ext_vector_type(8))) short short8;
typedef __attribute__((ext_vector_type(4))) float f32x4;

#define SCALE_F 0.088388347648318447f   // 1/sqrt(128)

__device__ __forceinline__ unsigned short f2bf(float f) {
  union { float f; unsigned u; } v; v.f = f;
  unsigned r = v.u + 0x7fffu + ((v.u >> 16) & 1u);   // RNE
  return (unsigned short)(r >> 16);
}

// async global->LDS, 16B per lane. dst must be wave-uniform; HW adds lane*16.
__device__ __forceinline__ void gload_lds16(const void* g, void* l) {
  __builtin_amdgcn_global_load_lds(
      (const __attribute__((address_space(1))) unsigned int*)g,
      (__attribute__((address_space(3))) unsigned int*)l, 16, 0, 0);
}

// ---------------- kernel 0: fp32 -> bf16 convert (encodings + 3 weights) ----------------
__global__ __launch_bounds__(256) void cvt_kernel(
    const float* __restrict__ enc, const float* __restrict__ wq,
    const float* __restrict__ wk, const float* __restrict__ wv,
    unsigned short* __restrict__ enc_bf, unsigned short* __restrict__ w_bf) {
  const int encN4 = 4194304;  // 16777216/4
  const int wN4 = 32768;      // 131072/4
  int total = encN4 + 3 * wN4;
  for (int i = blockIdx.x * blockDim.x + threadIdx.x; i < total;
       i += gridDim.x * blockDim.x) {
    const float4* src; unsigned short* dst; int j;
    if (i < encN4)              { src = (const float4*)enc; dst = enc_bf;          j = i; }
    else if (i < encN4 + wN4)   { src = (const float4*)wq;  dst = w_bf;            j = i - encN4; }
    else if (i < encN4 + 2*wN4) { src = (const float4*)wk;  dst = w_bf + 131072;   j = i - encN4 - wN4; }
    else                        { src = (const float4*)wv;  dst = w_bf + 262144;   j = i - encN4 - 2*wN4; }
    float4 v = src[j];
    uint2 p;
    p.x = (unsigned)f2bf(v.x) | ((unsigned)f2bf(v.y) << 16);
    p.y = (unsigned)f2bf(v.z) | ((unsigned)f2bf(v.w) << 16);
    *(uint2*)(dst + (size_t)j * 4) = p;
  }
}

// ---------------- kernel 1: QKV projection GEMM (m97 structure + gload_lds) ----------------
// unchanged (isolating the attn delta)
__global__ __launch_bounds__(256, 3) void proj_kernel(
    const unsigned short* __restrict__ enc_bf, const unsigned short* __restrict__ w_bf,
    unsigned short* __restrict__ q_bf, unsigned short* __restrict__ k_bf,
    unsigned short* __restrict__ vt_bf) {
  __shared__ __attribute__((aligned(16))) unsigned char a_tile[16384]; // [128 rows][128B] swizzled
  __shared__ __attribute__((aligned(16))) unsigned char b_tile[16384];

  const int rb = blockIdx.x;
  const int gy = blockIdx.y;
  const int tid = threadIdx.x;
  const int wid = tid >> 6, lane = tid & 63;
  const int c = lane & 15, g = lane >> 4;
  const int wr = wid >> 1, wc = wid & 1;

  const char* abase = (const char*)enc_bf + (size_t)rb * 128 * 2048;
  const char* bbase = (const char*)(w_bf + gy * 131072);

  int srow[4], scg[4];
#pragma unroll
  for (int i = 0; i < 4; ++i) {
    int o = i * 4096 + wid * 1024 + lane * 16;
    int row = o >> 7, cs = o & 127;
    srow[i] = row;
    scg[i] = cs ^ ((row & 7) << 4);
  }

  f32x4 acc[4][4];
#pragma unroll
  for (int a = 0; a < 4; ++a)
#pragma unroll
    for (int b = 0; b < 4; ++b) acc[a][b] = (f32x4){0.f, 0.f, 0.f, 0.f};

  for (int kk = 0; kk < 16; ++kk) {
#pragma unroll
    for (int i = 0; i < 4; ++i) {
      gload_lds16(abase + (size_t)srow[i] * 2048 + kk * 128 + scg[i],
                  a_tile + i * 4096 + wid * 1024);
      gload_lds16(bbase + (size_t)srow[i] * 2048 + kk * 128 + scg[i],
                  b_tile + i * 4096 + wid * 1024);
    }
    __syncthreads();
#pragma unroll
    for (int ks = 0; ks < 2; ++ks) {
      short8 af[4], bfr[4];
      int kb = ks * 64 + g * 16;
#pragma unroll
      for (int t = 0; t < 4; ++t) {
        int ar = wr * 64 + t * 16 + c;
        af[t] = *(const short8*)(a_tile + ar * 128 + (kb ^ ((ar & 7) << 4)));
        int br = wc * 64 + t * 16 + c;
        bfr[t] = *(const short8*)(b_tile + br * 128 + (kb ^ ((br & 7) << 4)));
      }
#pragma unroll
      for (int at = 0; at < 4; ++at)
#pragma unroll
        for (int bt = 0; bt < 4; ++bt)
          acc[at][bt] = __builtin_amdgcn_mfma_f32_16x16x32_bf16(
              af[at], bfr[bt], acc[at][bt], 0, 0, 0);
    }
    __syncthreads();
  }

  const size_t rowbase = (size_t)rb * 128;
  if (gy < 2) {
    unsigned short* dst = (gy == 0) ? q_bf : k_bf;
#pragma unroll
    for (int at = 0; at < 4; ++at)
#pragma unroll
      for (int bt = 0; bt < 4; ++bt) {
        int r = wr * 64 + at * 16 + g * 4;
        int col = wc * 64 + bt * 16 + c;
#pragma unroll
        for (int i = 0; i < 4; ++i)
          dst[(rowbase + r + i) * 128 + col] = f2bf(acc[at][bt][i]);
      }
  } else {
#pragma unroll
    for (int at = 0; at < 4; ++at)
#pragma unroll
      for (int bt = 0; bt < 4; ++bt) {
        size_t m = rowbase + wr * 64 + at * 16 + g * 4;
        int bb = (int)(m >> 11);
        int s = (int)(m & 2047);
        int d = wc * 64 + bt * 16 + c;
        uint2 p;
        p.x = (unsigned)f2bf(acc[at][bt][0]) | ((unsigned)f2bf(acc[at][bt][1]) << 16);
        p.y = (unsigned)f2bf(acc[at][bt][2]) | ((unsigned)f2bf(acc[at][bt][3]) << 16);
        *(uint2*)(vt_bf + ((size_t)bb * 128 + d) * 2048 + s) = p;
      }
  }
}

// ---------------- kernel 2: attention v2.1 — barrier-free, direct-L2 K/V ----------------
// 1024 blocks x 256 thr. Block = one (b, qt) 16-row q-tile; its 4 waves split the
// kv chunks (32 kv each) round-robin, fully independent (NO barriers in main loop).
// P round-trip: u16 write / u16 read + compiler memory fences (TBAA-safe; fixes
// round-6 NaN from reads being scheduled before writes).
__global__ __launch_bounds__(256) void attn_kernel(
    const unsigned short* __restrict__ q_bf, const unsigned short* __restrict__ k_bf,
    const unsigned short* __restrict__ vt_bf, float* __restrict__ out) {
  __shared__ __attribute__((aligned(16))) float comb[4][16][128];  // 32 KB partial O
  __shared__ float rs[4][16];                                      // partial rowsums
  __shared__ __attribute__((aligned(16))) unsigned char p_lds[4][1088]; // per-wave P [16 q][68B]

  const int blk = blockIdx.x;
  const int b = blk & 7;
  const int j = blk >> 3;                       // 0..127
  const int qt = (j & 1) ? (127 - (j >> 1)) : (j >> 1);  // balanced long/short interleave
  const int t0 = qt * 16;

  const int tid = threadIdx.x;
  const int wid = tid >> 6, lane = tid & 63;
  const int c = lane & 15, g = lane >> 4;

  // Q fragments (A-operand): lane (c,g) row = t0+c, k-slice ks*32 + g*8
  const unsigned short* qrow = q_bf + (size_t)(b * 2048 + t0 + c) * 128;
  short8 qf[4];
#pragma unroll
  for (int ks = 0; ks < 4; ++ks) qf[ks] = *(const short8*)(qrow + ks * 32 + g * 8);

  f32x4 accO[8];
#pragma unroll
  for (int i = 0; i < 8; ++i) accO[i] = (f32x4){0.f, 0.f, 0.f, 0.f};
  float rsum[4] = {0.f, 0.f, 0.f, 0.f};

  const unsigned short* kb = k_bf + (size_t)b * 262144;   // K[s][d] 2048x128
  const unsigned short* vb = vt_bf + (size_t)b * 262144;  // VT[d][s] 128x2048
  unsigned char* pt = p_lds[wid];

  const int nch = (t0 + 16 + 31) >> 5;   // kv chunks of 32 covering s <= t0+15

  for (int ch = wid; ch < nch; ch += 4) {
    const int kv0 = ch << 5;
    // K fragments (B-operand of QK^T): lane (c,g): s = kv0+nt*16+c, d = ks*32+g*8..+8
    short8 kf[2][4];
#pragma unroll
    for (int nt = 0; nt < 2; ++nt)
#pragma unroll
      for (int ks = 0; ks < 4; ++ks)
        kf[nt][ks] = *(const short8*)(kb + (size_t)(kv0 + nt * 16 + c) * 128 + ks * 32 + g * 8);
    // V fragments (B-operand of PV): lane (c,g): d = dnt*16+c, s = kv0+g*8..+8
    short8 vf[8];
#pragma unroll
    for (int dnt = 0; dnt < 8; ++dnt)
      vf[dnt] = *(const short8*)(vb + (size_t)(dnt * 16 + c) * 2048 + kv0 + g * 8);

    // S = Q K^T : 16 q-rows x 32 kv
    f32x4 accS[2];
    accS[0] = (f32x4){0.f, 0.f, 0.f, 0.f};
    accS[1] = (f32x4){0.f, 0.f, 0.f, 0.f};
#pragma unroll
    for (int nt = 0; nt < 2; ++nt)
#pragma unroll
      for (int ks = 0; ks < 4; ++ks)
        accS[nt] = __builtin_amdgcn_mfma_f32_16x16x32_bf16(qf[ks], kf[nt][ks], accS[nt], 0, 0, 0);

    // scale, causal mask, square, rowsum; write P rows (row-major [q][s], 68B stride)
    const int rowg = t0 + g * 4;
#pragma unroll
    for (int nt = 0; nt < 2; ++nt) {
      const int colg = kv0 + nt * 16 + c;
#pragma unroll
      for (int i = 0; i < 4; ++i) {
        float s = accS[nt][i] * SCALE_F;
        s = (colg <= rowg + i) ? s : 0.f;
        float p = s * s;
        rsum[i] += p;
        *(unsigned short*)(pt + (g * 4 + i) * 68 + (nt * 16 + c) * 2) = f2bf(p);
      }
    }
    __asm__ volatile("" ::: "memory");  // P writes ordered before P reads (no TBAA reorder)
    // P fragment (A-operand): lane (c,g): row c, k = g*8+j  (u16 reads, v1-proven)
    unsigned short uu[8];
#pragma unroll
    for (int jj = 0; jj < 8; ++jj)
      uu[jj] = *(const unsigned short*)(pt + c * 68 + (g * 8 + jj) * 2);
    __asm__ volatile("" ::: "memory");  // P reads ordered before next iteration's writes
    short8 pf;
#pragma unroll
    for (int jj = 0; jj < 8; ++jj) pf[jj] = (short)uu[jj];

    // O += P(16x32) * V(32x128)
#pragma unroll
    for (int dnt = 0; dnt < 8; ++dnt)
      accO[dnt] = __builtin_amdgcn_mfma_f32_16x16x32_bf16(pf, vf[dnt], accO[dnt], 0, 0, 0);
  }

  // rowsum: reduce across the 16 column-lanes (low 4 bits of lane)
#pragma unroll
  for (int m = 1; m < 16; m <<= 1)
#pragma unroll
    for (int i = 0; i < 4; ++i) rsum[i] += __shfl_xor(rsum[i], m, 64);

  // stash this wave's kv-partial
#pragma unroll
  for (int dnt = 0; dnt < 8; ++dnt)
#pragma unroll
    for (int i = 0; i < 4; ++i)
      comb[wid][g * 4 + i][dnt * 16 + c] = accO[dnt][i];
  if (c == 0) {
#pragma unroll
    for (int i = 0; i < 4; ++i) rs[wid][g * 4 + i] = rsum[i];
  }
  __syncthreads();

  // combine + normalize + write: thread -> row r = tid>>4, d-span = (tid&15)*8..+8
  const int r = tid >> 4;
  const int d0 = (tid & 15) * 8;
  float rtot = rs[0][r] + rs[1][r] + rs[2][r] + rs[3][r];
  float inv = 1.0f / sqrtf(rtot);
  float o[8];
#pragma unroll
  for (int k = 0; k < 8; ++k)
    o[k] = comb[0][r][d0 + k] + comb[1][r][d0 + k] + comb[2][r][d0 + k] + comb[3][r][d0 + k];
  const size_t ob = (size_t)(b * 2048 + t0 + r) * 128 + d0;
#pragma unroll
  for (int k = 0; k < 8; ++k) out[ob + k] = o[k] * inv;
}

extern "C" void kernel_launch(void* const* d_in, const int* in_sizes, int n_in,
                              void* d_out, int out_size, void* d_ws, size_t ws_size,
                              hipStream_t stream) {
  const float* enc = (const float*)d_in[0];
  const float* wq  = (const float*)d_in[1];
  const float* wk  = (const float*)d_in[2];
  const float* wv  = (const float*)d_in[3];
  float* out = (float*)d_out;
  char* ws = (char*)d_ws;

  unsigned short* enc_bf = (unsigned short*)ws;                       // 33,554,432 B
  unsigned short* w_bf   = (unsigned short*)(ws + 33554432);          //    786,432 B
  unsigned short* q_bf   = (unsigned short*)(ws + 34340864);          //  4,194,304 B
  unsigned short* k_bf   = (unsigned short*)(ws + 38535168);          //  4,194,304 B
  unsigned short* vt_bf  = (unsigned short*)(ws + 42729472);          //  4,194,304 B

  cvt_kernel<<<2048, 256, 0, stream>>>(enc, wq, wk, wv, enc_bf, w_bf);
  proj_kernel<<<dim3(128, 3), 256, 0, stream>>>(enc_bf, w_bf, q_bf, k_bf, vt_bf);
  attn_kernel<<<1024, 256, 0, stream>>>(q_bf, k_bf, vt_bf, out);
}